// Round 4
// baseline (2926.498 us; speedup 1.0000x reference)
//
#include <hip/hip_runtime.h>
#include <hip/hip_cooperative_groups.h>
#include <cstdint>
#include <cstddef>

namespace cg = cooperative_groups;

// Problem constants (from reference: B=4, C=64, H=288, W=432, TEM=6)
#define NB 4
#define NC 64
#define HH 288
#define WW 432
#define PW 72                      // W / TEM
#define NV (HH*WW)                 // 124416 vertices
#define R_PER ((HH-1)*PW)          // 20664 row (vertical) edges per phase
#define C_PER (HH*(PW-1))          // 20448 col (horizontal) edges per phase
#define X_PER (HH*PW)              // 20736 cross edges per phase pair
#define PAIRW (R_PER + C_PER)      // 41112 weight-layout per-phase block
#define ROWS_TOT (6*R_PER)         // 123984
#define ROWCOL (6*PAIRW)           // 246672
#define NE (ROWCOL + 5*X_PER)      // 350352 edges
#define NTREE (NV-1)               // 124415
#define NROUNDS 18                 // >= ceil(log2 V)=17 guaranteed convergence
#define CHUNK 4096
#define NCHUNK ((NE + CHUNK - 1)/CHUNK)   // 86
#define COOP_BLOCKS 1024

typedef unsigned long long ull;

// ---- edge id -> endpoints, per the INDEX layout (rows ++ cols ++ cross) ----
__device__ __forceinline__ void index_uv(int e, int& u, int& v) {
    if (e < ROWS_TOT) {
        int t = e / R_PER, l = e - t * R_PER;
        int h = l / PW, x = l - h * PW;
        u = h * WW + t * PW + x; v = u + WW;
    } else if (e < ROWCOL) {
        int q = e - ROWS_TOT;
        int t = q / C_PER, l = q - t * C_PER;
        int h = l / (PW-1), x = l - h * (PW-1);
        u = h * WW + t * PW + x; v = u + 1;
    } else {
        int q = e - ROWCOL;
        int t = q / X_PER, l = q - t * X_PER;
        int h = l / PW, x = l - h * PW;
        u = h * WW + t * PW + x; v = u + PW;
    }
}

// root under parent forest; handles unbroken 2-cycles (mutual min edge) by
// rooting the smaller id — exactly the reference's (gp==idx)&(idx<parent) rule.
__device__ __forceinline__ int rootOf(const int* __restrict__ par, int c) {
    while (true) {
        int p = par[c];
        if (p == c) return c;
        int pp = par[p];
        if (pp == c) return c < p ? c : p;
        c = p;
    }
}

__global__ __launch_bounds__(256) void init_kernel(int* comp, int* parent,
                                                   ull* minkey, unsigned char* mask,
                                                   unsigned char* alive,
                                                   int* found, int* done) {
    int i = blockIdx.x * 256 + threadIdx.x;
    int b = blockIdx.y;
    if (i < NV) {
        comp[(size_t)b*NV + i] = i;
        parent[(size_t)b*NV + i] = i;
        minkey[(size_t)b*NV + i] = ~0ULL;
    }
    if (i < NE) {
        mask[(size_t)b*NE + i] = 0;
        alive[(size_t)b*NE + i] = 1;
    }
    if (i < 2*NB) found[i] = 0;    // idempotent across b
    if (i < NB)   done[i] = 0;
}

// Stencil key kernel fused with Borůvka round 0.
// Thread = vertex (h,x). Computes the 3 incident forward diffs (vertical,
// horizontal, cross) in one pass over channels, writes keys (weight slot ==
// edge id, algebra verified vs the reference's weight layout), and — since
// round-0 components are singletons — atomicMins the key straight into
// minkey[u], minkey[v] using the INDEX-layout endpoints.
__global__ __launch_bounds__(256) void key0_kernel(const float* __restrict__ fm,
                                                   ull* __restrict__ keys,
                                                   ull* __restrict__ minkey) {
    int i = blockIdx.x * 256 + threadIdx.x;
    int b = blockIdx.y;
    if (i >= NV) return;
    int h = i / WW, x = i - h * WW;
    int t = x / PW, xr = x - t * PW;
    bool hv = (h < HH-1);
    bool hh = (xr < PW-1);
    bool hx = (x < WW-PW);
    int ov = hv ? WW : 0;          // invalid -> reload self, diff = 0
    int oh = hh ? 1  : 0;
    int ox = hx ? PW : 0;
    const float* base = fm + (size_t)b * NC * NV + i;
    float sv = 0.f, sh_ = 0.f, sx = 0.f;
    #pragma unroll 8
    for (int ch = 0; ch < NC; ++ch) {
        const float* p = base + (size_t)ch * NV;
        float f0 = p[0];
        float dv = f0 - p[ov];
        float dh = f0 - p[oh];
        float dx = f0 - p[ox];
        sv += dv * dv; sh_ += dh * dh; sx += dx * dx;
    }
    ull* mk = minkey + (size_t)b * NV;
    ull* ky = keys + (size_t)b * NE;
    if (hv) {
        int e = t * PAIRW + h * PW + xr;
        ull k = ((ull)__float_as_uint(sv) << 32) | (unsigned int)e;
        ky[e] = k;
        int u, v; index_uv(e, u, v);
        atomicMin(&mk[u], k); atomicMin(&mk[v], k);
    }
    if (hh) {
        int e = t * PAIRW + R_PER + h * (PW-1) + xr;
        ull k = ((ull)__float_as_uint(sh_) << 32) | (unsigned int)e;
        ky[e] = k;
        int u, v; index_uv(e, u, v);
        atomicMin(&mk[u], k); atomicMin(&mk[v], k);
    }
    if (hx) {
        int e = ROWCOL + t * X_PER + h * PW + xr;
        ull k = ((ull)__float_as_uint(sx) << 32) | (unsigned int)e;
        ky[e] = k;
        int u, v; index_uv(e, u, v);
        atomicMin(&mk[u], k); atomicMin(&mk[v], k);
    }
}

// One cooperative kernel: select round 0, rounds 1..17 (scan+select) with
// uniform early break on convergence, then mask compaction -> sorted output.
__global__ __launch_bounds__(256, 4)
void mst_coop_kernel(const ull* __restrict__ keys, int* __restrict__ comp,
                     int* __restrict__ parent, ull* __restrict__ minkey,
                     unsigned char* __restrict__ mask, unsigned char* __restrict__ alive,
                     int* __restrict__ found, int* __restrict__ done,
                     int* __restrict__ counts, int* __restrict__ offsets,
                     int* __restrict__ out) {
    cg::grid_group grid = cg::this_grid();
    const int tid = threadIdx.x;
    const int T = gridDim.x * 256;
    const int gtid = blockIdx.x * 256 + tid;
    __shared__ int sh[256];

    // ---- select, round 0 (minkey prefilled by key0_kernel; comp = identity) ----
    for (int b = 0; b < NB; ++b) {
        size_t off = (size_t)b * NV;
        for (int c = gtid; c < NV; c += T) {
            ull k = minkey[off + c];
            int par = c;
            if (k != ~0ULL) {
                minkey[off + c] = ~0ULL;
                int e = (int)(k & 0xffffffffu);
                mask[(size_t)b * NE + e] = 1;
                int u, v; index_uv(e, u, v);
                int cu = comp[off + u], cv = comp[off + v];
                par = (cu == c) ? cv : cu;
            }
            parent[off + c] = par;
        }
    }
    grid.sync();

    // ---- rounds 1..17 ----
    for (int r = 1; r < NROUNDS; ++r) {
        const int cur = r & 1, nxt = cur ^ 1;
        // scan phase
        for (int b = 0; b < NB; ++b) {
            if (done[b]) continue;
            const int* par = parent + (size_t)b * NV;
            int* cmp = comp + (size_t)b * NV;
            ull* mk = minkey + (size_t)b * NV;
            unsigned char* alv = alive + (size_t)b * NE;
            const ull* ky = keys + (size_t)b * NE;
            for (int e = gtid; e < NE; e += T) {
                if (!alv[e]) continue;
                int u, v; index_uv(e, u, v);
                int cu = rootOf(par, cmp[u]); if (cmp[u] != cu) cmp[u] = cu;
                int cv = rootOf(par, cmp[v]); if (cmp[v] != cv) cmp[v] = cv;
                if (cu != cv) {
                    found[cur*NB + b] = 1;          // wave-coalesced store
                    ull k = ky[e];
                    if (k < mk[cu]) atomicMin(&mk[cu], k);
                    if (k < mk[cv]) atomicMin(&mk[cv], k);
                } else {
                    alv[e] = 0;                      // permanently intra-component
                }
            }
        }
        grid.sync();
        int fc0 = found[cur*NB+0], fc1 = found[cur*NB+1],
            fc2 = found[cur*NB+2], fc3 = found[cur*NB+3];
        if (!(fc0 | fc1 | fc2 | fc3)) break;         // uniform: all converged
        // select phase
        if (gtid < NB) {
            found[nxt*NB + gtid] = 0;                // reset for round r+1
            int fcb = (gtid==0)?fc0:(gtid==1)?fc1:(gtid==2)?fc2:fc3;
            if (!fcb) done[gtid] = 1;
        }
        for (int b = 0; b < NB; ++b) {
            int fcb = (b==0)?fc0:(b==1)?fc1:(b==2)?fc2:fc3;
            if (!fcb) continue;
            size_t off = (size_t)b * NV;
            for (int c = gtid; c < NV; c += T) {
                ull k = minkey[off + c];
                int par = c;
                if (k != ~0ULL) {
                    minkey[off + c] = ~0ULL;         // reset only touched slots
                    int e = (int)(k & 0xffffffffu);
                    mask[(size_t)b * NE + e] = 1;    // idempotent
                    int u, v; index_uv(e, u, v);
                    int cu = comp[off + u], cv = comp[off + v];
                    par = (cu == c) ? cv : cu;
                }
                if (parent[off + c] != par) parent[off + c] = par;
            }
        }
        grid.sync();
    }

    // ---- compaction: per-chunk count -> serial offsets -> ordered write ----
    for (int task = blockIdx.x; task < NB*NCHUNK; task += gridDim.x) {
        int b = task / NCHUNK, ck = task - b * NCHUNK;
        const unsigned char* m = mask + (size_t)b * NE;
        int base_e = ck * CHUNK + tid * 16;
        int cnt = 0;
        #pragma unroll
        for (int i = 0; i < 16; ++i) {
            int e = base_e + i;
            if (e < NE && m[e]) cnt++;
        }
        sh[tid] = cnt;
        __syncthreads();
        for (int o = 128; o > 0; o >>= 1) {
            if (tid < o) sh[tid] += sh[tid + o];
            __syncthreads();
        }
        if (tid == 0) counts[b * NCHUNK + ck] = sh[0];
        __syncthreads();
    }
    grid.sync();
    if (gtid < NB) {
        int b = gtid, run = 0;
        for (int ck = 0; ck < NCHUNK; ++ck) {
            int c = counts[b * NCHUNK + ck];
            offsets[b * NCHUNK + ck] = run;
            run += c;
        }
    }
    grid.sync();
    for (int task = blockIdx.x; task < NB*NCHUNK; task += gridDim.x) {
        int b = task / NCHUNK, ck = task - b * NCHUNK;
        const unsigned char* m = mask + (size_t)b * NE;
        int base_e = ck * CHUNK + tid * 16;
        int cnt = 0;
        #pragma unroll
        for (int i = 0; i < 16; ++i) {
            int e = base_e + i;
            if (e < NE && m[e]) cnt++;
        }
        sh[tid] = cnt;
        __syncthreads();
        for (int o = 1; o < 256; o <<= 1) {          // Hillis-Steele inclusive scan
            int v = 0;
            if (tid >= o) v = sh[tid - o];
            __syncthreads();
            sh[tid] += v;
            __syncthreads();
        }
        int pos = offsets[b * NCHUNK + ck] + (sh[tid] - cnt);
        for (int i = 0; i < 16; ++i) {
            int e = base_e + i;
            if (e < NE && m[e]) {
                if (pos < NTREE) out[(size_t)b * NTREE + pos] = e;
                pos++;
            }
        }
        __syncthreads();
    }
}

extern "C" void kernel_launch(void* const* d_in, const int* in_sizes, int n_in,
                              void* d_out, int out_size, void* d_ws, size_t ws_size,
                              hipStream_t stream) {
    const float* fm = (const float*)d_in[0];
    int* out = (int*)d_out;   // reference output dtype is int32

    char* ws = (char*)d_ws;
    size_t off = 0;
    auto alloc = [&](size_t bytes) -> void* {
        void* p = ws + off;
        off += (bytes + 255) & ~(size_t)255;
        return p;
    };
    ull* keys    = (ull*)alloc((size_t)NB * NE * 8);
    ull* minkey  = (ull*)alloc((size_t)NB * NV * 8);
    int* comp    = (int*)alloc((size_t)NB * NV * 4);
    int* parent  = (int*)alloc((size_t)NB * NV * 4);
    unsigned char* mask  = (unsigned char*)alloc((size_t)NB * NE);
    unsigned char* alive = (unsigned char*)alloc((size_t)NB * NE);
    int* counts  = (int*)alloc((size_t)NB * NCHUNK * 4);
    int* offsets = (int*)alloc((size_t)NB * NCHUNK * 4);
    int* found   = (int*)alloc(2 * NB * 4);
    int* done    = (int*)alloc(NB * 4);

    dim3 blk(256);
    dim3 gE((NE + 255) / 256, NB);
    dim3 gV((NV + 255) / 256, NB);

    init_kernel<<<gE, blk, 0, stream>>>(comp, parent, minkey, mask, alive, found, done);
    key0_kernel<<<gV, blk, 0, stream>>>(fm, keys, minkey);

    void* args[] = {(void*)&keys, (void*)&comp, (void*)&parent, (void*)&minkey,
                    (void*)&mask, (void*)&alive, (void*)&found, (void*)&done,
                    (void*)&counts, (void*)&offsets, (void*)&out};
    hipLaunchCooperativeKernel((const void*)mst_coop_kernel,
                               dim3(COOP_BLOCKS), dim3(256), args, 0, stream);
}

// Round 5
// 633.386 us; speedup vs baseline: 4.6204x; 4.6204x over previous
//
#include <hip/hip_runtime.h>
#include <cstdint>
#include <cstddef>

// Problem constants (from reference: B=4, C=64, H=288, W=432, TEM=6)
#define NB 4
#define NC 64
#define HH 288
#define WW 432
#define PW 72                      // W / TEM
#define NV (HH*WW)                 // 124416 vertices
#define R_PER ((HH-1)*PW)          // 20664 row (vertical) edges per phase
#define C_PER (HH*(PW-1))          // 20448 col (horizontal) edges per phase
#define X_PER (HH*PW)              // 20736 cross edges per phase pair
#define PAIRW (R_PER + C_PER)      // 41112 weight-layout per-phase block
#define ROWS_TOT (6*R_PER)         // 123984
#define ROWCOL (6*PAIRW)           // 246672
#define NE (ROWCOL + 5*X_PER)      // 350352 edges
#define NTREE (NV-1)               // 124415
#define NROUNDS 18                 // round 0 fused in key0 + rounds 1..17
#define NWORDS ((NE + 31)/32)      // 10949 alive-bitmask words per batch
#define CHUNK 4096
#define NCHUNK ((NE + CHUNK - 1)/CHUNK)   // 86

typedef unsigned long long ull;

// ---- edge id -> endpoints, per the INDEX layout (rows ++ cols ++ cross) ----
__device__ __forceinline__ void index_uv(int e, int& u, int& v) {
    if (e < ROWS_TOT) {
        int t = e / R_PER, l = e - t * R_PER;
        int h = l / PW, x = l - h * PW;
        u = h * WW + t * PW + x; v = u + WW;
    } else if (e < ROWCOL) {
        int q = e - ROWS_TOT;
        int t = q / C_PER, l = q - t * C_PER;
        int h = l / (PW-1), x = l - h * (PW-1);
        u = h * WW + t * PW + x; v = u + 1;
    } else {
        int q = e - ROWCOL;
        int t = q / X_PER, l = q - t * X_PER;
        int h = l / PW, x = l - h * PW;
        u = h * WW + t * PW + x; v = u + PW;
    }
}

// root under parent forest; handles unbroken 2-cycles (mutual min edge) by
// rooting the smaller id — exactly the reference's (gp==idx)&(idx<parent) rule.
__device__ __forceinline__ int rootOf(const int* __restrict__ par, int c) {
    while (true) {
        int p = par[c];
        if (p == c) return c;
        int pp = par[p];
        if (pp == c) return c < p ? c : p;
        c = p;
    }
}

__global__ __launch_bounds__(256) void init_kernel(int* comp, int* parent,
                                                   ull* minkey, unsigned char* mask,
                                                   unsigned* aliveW,
                                                   int* found, int* done) {
    int i = blockIdx.x * 256 + threadIdx.x;
    int b = blockIdx.y;
    if (i < NV) {
        comp[(size_t)b*NV + i] = i;
        parent[(size_t)b*NV + i] = i;
        minkey[(size_t)b*NV + i] = ~0ULL;
    }
    if (i < NE) mask[(size_t)b*NE + i] = 0;
    if (i < NWORDS) aliveW[(size_t)b*NWORDS + i] = 0xffffffffu;
    if (b == 0 && i < NB) { found[i] = 1; found[NB + i] = 0; done[i] = 0; }
}

// Stencil key kernel fused with Borůvka round 0 (measured ~25 us in v4).
// Thread = vertex (h,x). Computes the 3 incident forward diffs (vertical,
// horizontal, cross) in one pass over channels, writes keys (weight slot ==
// edge id), and — since round-0 components are singletons — atomicMins the
// key straight into minkey[u], minkey[v] using the INDEX-layout endpoints.
__global__ __launch_bounds__(256) void key0_kernel(const float* __restrict__ fm,
                                                   ull* __restrict__ keys,
                                                   ull* __restrict__ minkey) {
    int i = blockIdx.x * 256 + threadIdx.x;
    int b = blockIdx.y;
    if (i >= NV) return;
    int h = i / WW, x = i - h * WW;
    int t = x / PW, xr = x - t * PW;
    bool hv = (h < HH-1);
    bool hh = (xr < PW-1);
    bool hx = (x < WW-PW);
    int ov = hv ? WW : 0;          // invalid -> reload self, diff = 0
    int oh = hh ? 1  : 0;
    int ox = hx ? PW : 0;
    const float* base = fm + (size_t)b * NC * NV + i;
    float sv = 0.f, sh_ = 0.f, sx = 0.f;
    #pragma unroll 8
    for (int ch = 0; ch < NC; ++ch) {
        const float* p = base + (size_t)ch * NV;
        float f0 = p[0];
        float dv = f0 - p[ov];
        float dh = f0 - p[oh];
        float dx = f0 - p[ox];
        sv += dv * dv; sh_ += dh * dh; sx += dx * dx;
    }
    ull* mk = minkey + (size_t)b * NV;
    ull* ky = keys + (size_t)b * NE;
    if (hv) {
        int e = t * PAIRW + h * PW + xr;
        ull k = ((ull)__float_as_uint(sv) << 32) | (unsigned int)e;
        ky[e] = k;
        int u, v; index_uv(e, u, v);
        atomicMin(&mk[u], k); atomicMin(&mk[v], k);
    }
    if (hh) {
        int e = t * PAIRW + R_PER + h * (PW-1) + xr;
        ull k = ((ull)__float_as_uint(sh_) << 32) | (unsigned int)e;
        ky[e] = k;
        int u, v; index_uv(e, u, v);
        atomicMin(&mk[u], k); atomicMin(&mk[v], k);
    }
    if (hx) {
        int e = ROWCOL + t * X_PER + h * PW + xr;
        ull k = ((ull)__float_as_uint(sx) << 32) | (unsigned int)e;
        ky[e] = k;
        int u, v; index_uv(e, u, v);
        atomicMin(&mk[u], k); atomicMin(&mk[v], k);
    }
}

// One Borůvka scan over all edges, coalesced. Dead edges exit on a broadcast
// bitmask word read; deaths are folded back via wave ballot (no atomics).
__global__ __launch_bounds__(256) void scan_kernel(const ull* __restrict__ keys,
                                                   int* __restrict__ comp,
                                                   const int* __restrict__ parent,
                                                   ull* __restrict__ minkey,
                                                   unsigned* __restrict__ aliveW,
                                                   int* __restrict__ foundCur,
                                                   const int* __restrict__ done) {
    int e = blockIdx.x * 256 + threadIdx.x;
    int b = blockIdx.y;
    if (done[b]) return;                         // converged: scalar read + exit
    const int lane = threadIdx.x & 63;
    unsigned* aw = aliveW + (size_t)b * NWORDS;
    bool was = false, live = false;
    int cu = 0, cv = 0;
    if (e < NE) was = (aw[e >> 5] >> (e & 31)) & 1;
    if (was) {
        const int* par = parent + (size_t)b * NV;
        int* cmp = comp + (size_t)b * NV;
        int u, v; index_uv(e, u, v);
        cu = rootOf(par, cmp[u]); if (cmp[u] != cu) cmp[u] = cu;  // benign race
        cv = rootOf(par, cmp[v]); if (cmp[v] != cv) cmp[v] = cv;
        live = (cu != cv);
    }
    if (live) {
        ull k = keys[(size_t)b * NE + e];
        ull* mk = minkey + (size_t)b * NV;
        if (k < mk[cu]) atomicMin(&mk[cu], k);   // pre-check kills hot-slot serialization
        if (k < mk[cv]) atomicMin(&mk[cv], k);
    }
    ull ball = __ballot(live ? 1 : 0);
    ull ballWas = __ballot(was ? 1 : 0);
    if (ball != ballWas) {                       // deaths in this wave: rewrite 2 words
        int wbase = (blockIdx.x * 256 + (threadIdx.x & ~63)) >> 5;
        if (lane == 0)  aw[wbase]     = (unsigned)ball;
        if (lane == 32) aw[wbase + 1] = (unsigned)(ball >> 32);
    }
    if (ball && lane == __ffsll((long long)ball) - 1)
        foundCur[b] = 1;                         // one store per wave
}

// Per component: read winning edge, mark mask, hook parent, reset minkey.
// fc==0 => scan found nothing => minkey untouched and hooks idempotent: set
// done, skip. foundNext is reset for the round after next.
__global__ __launch_bounds__(256) void select_kernel(const int* __restrict__ comp,
                                                     int* __restrict__ parent,
                                                     ull* __restrict__ minkey,
                                                     unsigned char* __restrict__ mask,
                                                     const int* __restrict__ foundCur,
                                                     int* __restrict__ foundNext,
                                                     int* __restrict__ done) {
    int c = blockIdx.x * 256 + threadIdx.x;
    int b = blockIdx.y;
    int fc = foundCur[b];
    if (c == 0) {
        foundNext[b] = 0;
        if (fc == 0) done[b] = 1;                // monotone; visible to later scans
    }
    if (fc == 0) return;
    if (c >= NV) return;
    size_t off = (size_t)b * NV;
    ull k = minkey[off + c];
    int par = c;
    if (k != ~0ULL) {
        minkey[off + c] = ~0ULL;                 // reset only touched slots
        int e = (int)(k & 0xffffffffu);
        mask[(size_t)b * NE + e] = 1;            // idempotent
        int u, v; index_uv(e, u, v);
        int cu = comp[off + u], cv = comp[off + v];
        par = (cu == c) ? cv : cu;               // "other" component
    }
    if (parent[off + c] != par) parent[off + c] = par;
}

__global__ __launch_bounds__(256) void count_kernel(const unsigned char* __restrict__ mask,
                                                    int* __restrict__ counts) {
    int b = blockIdx.y, ck = blockIdx.x, t = threadIdx.x;
    const unsigned char* m = mask + (size_t)b * NE;
    int base_e = ck * CHUNK + t * 16;
    int cnt = 0;
    #pragma unroll
    for (int i = 0; i < 16; ++i) {
        int e = base_e + i;
        if (e < NE && m[e]) cnt++;
    }
    __shared__ int sh[256];
    sh[t] = cnt;
    __syncthreads();
    for (int o = 128; o > 0; o >>= 1) {
        if (t < o) sh[t] += sh[t + o];
        __syncthreads();
    }
    if (t == 0) counts[b * NCHUNK + ck] = sh[0];
}

// Write with inline offset computation (reduce over counts[0..ck-1]) — no
// separate offs kernel.
__global__ __launch_bounds__(256) void write_kernel(const unsigned char* __restrict__ mask,
                                                    const int* __restrict__ counts,
                                                    int* __restrict__ out) {
    int b = blockIdx.y, ck = blockIdx.x, t = threadIdx.x;
    __shared__ int sh[256];
    __shared__ int shOff[128];
    // block offset = sum of counts for chunks < ck (NCHUNK=86 < 128)
    shOff[t & 127] = 0;
    __syncthreads();
    if (t < NCHUNK && t < ck) shOff[t] = counts[b * NCHUNK + t];
    __syncthreads();
    for (int o = 64; o > 0; o >>= 1) {
        if (t < o) shOff[t] += shOff[t + o];
        __syncthreads();
    }
    int blockOff = shOff[0];

    const unsigned char* m = mask + (size_t)b * NE;
    int base_e = ck * CHUNK + t * 16;
    int cnt = 0;
    #pragma unroll
    for (int i = 0; i < 16; ++i) {
        int e = base_e + i;
        if (e < NE && m[e]) cnt++;
    }
    sh[t] = cnt;
    __syncthreads();
    for (int o = 1; o < 256; o <<= 1) {          // Hillis-Steele inclusive scan
        int v = 0;
        if (t >= o) v = sh[t - o];
        __syncthreads();
        sh[t] += v;
        __syncthreads();
    }
    int pos = blockOff + (sh[t] - cnt);
    for (int i = 0; i < 16; ++i) {
        int e = base_e + i;
        if (e < NE && m[e]) {
            if (pos < NTREE) out[(size_t)b * NTREE + pos] = e;
            pos++;
        }
    }
}

extern "C" void kernel_launch(void* const* d_in, const int* in_sizes, int n_in,
                              void* d_out, int out_size, void* d_ws, size_t ws_size,
                              hipStream_t stream) {
    const float* fm = (const float*)d_in[0];
    int* out = (int*)d_out;   // reference output dtype is int32

    char* ws = (char*)d_ws;
    size_t off = 0;
    auto alloc = [&](size_t bytes) -> void* {
        void* p = ws + off;
        off += (bytes + 255) & ~(size_t)255;
        return p;
    };
    ull* keys    = (ull*)alloc((size_t)NB * NE * 8);
    ull* minkey  = (ull*)alloc((size_t)NB * NV * 8);
    int* comp    = (int*)alloc((size_t)NB * NV * 4);
    int* parent  = (int*)alloc((size_t)NB * NV * 4);
    unsigned char* mask = (unsigned char*)alloc((size_t)NB * NE);
    unsigned* aliveW = (unsigned*)alloc((size_t)NB * NWORDS * 4);
    int* counts  = (int*)alloc((size_t)NB * NCHUNK * 4);
    int* found   = (int*)alloc(2 * NB * 4);
    int* done    = (int*)alloc(NB * 4);

    dim3 blk(256);
    dim3 gE((NE + 255) / 256, NB);
    dim3 gV((NV + 255) / 256, NB);

    init_kernel<<<gE, blk, 0, stream>>>(comp, parent, minkey, mask, aliveW, found, done);
    key0_kernel<<<gV, blk, 0, stream>>>(fm, keys, minkey);

    // Round 0 select (found[0..NB) preset to 1 by init; comp = identity).
    select_kernel<<<gV, blk, 0, stream>>>(comp, parent, minkey, mask,
                                          found, found + NB, done);
    // Rounds 1..17
    for (int r = 1; r < NROUNDS; ++r) {
        int* fCur  = found + (r & 1) * NB;
        int* fNext = found + ((r + 1) & 1) * NB;
        scan_kernel<<<gE, blk, 0, stream>>>(keys, comp, parent, minkey, aliveW,
                                            fCur, done);
        select_kernel<<<gV, blk, 0, stream>>>(comp, parent, minkey, mask,
                                              fCur, fNext, done);
    }

    count_kernel<<<dim3(NCHUNK, NB), blk, 0, stream>>>(mask, counts);
    write_kernel<<<dim3(NCHUNK, NB), blk, 0, stream>>>(mask, counts, out);
}

// Round 6
// 629.004 us; speedup vs baseline: 4.6526x; 1.0070x over previous
//
#include <hip/hip_runtime.h>
#include <cstdint>
#include <cstddef>

// Problem constants (from reference: B=4, C=64, H=288, W=432, TEM=6)
#define NB 4
#define NC 64
#define HH 288
#define WW 432
#define PW 72                      // W / TEM
#define NV (HH*WW)                 // 124416 vertices
#define R_PER ((HH-1)*PW)          // 20664 row (vertical) edges per phase
#define C_PER (HH*(PW-1))          // 20448 col (horizontal) edges per phase
#define X_PER (HH*PW)              // 20736 cross edges per phase pair
#define PAIRW (R_PER + C_PER)      // 41112 weight-layout per-phase block
#define ROWS_TOT (6*R_PER)         // 123984
#define ROWCOL (6*PAIRW)           // 246672
#define NE (ROWCOL + 5*X_PER)      // 350352 edges
#define NEB ((NE + 255)/256)       // 1369 blocks per batch for edge kernels
#define NEP (NEB*256)              // 350464 padded edge space (grid-aligned)
#define NWORDS_P (NEP/32)          // 10952 alive-bitmask words per batch (padded)
#define NTREE (NV-1)               // 124415
#define NROUNDS 18                 // round 0 fused in key0 + rounds 1..17
#define CHUNK 4096
#define NCHUNK ((NE + CHUNK - 1)/CHUNK)   // 86

typedef unsigned long long ull;

// ---- edge id -> endpoints, per the INDEX layout (rows ++ cols ++ cross) ----
__device__ __forceinline__ void index_uv(int e, int& u, int& v) {
    if (e < ROWS_TOT) {
        int t = e / R_PER, l = e - t * R_PER;
        int h = l / PW, x = l - h * PW;
        u = h * WW + t * PW + x; v = u + WW;
    } else if (e < ROWCOL) {
        int q = e - ROWS_TOT;
        int t = q / C_PER, l = q - t * C_PER;
        int h = l / (PW-1), x = l - h * (PW-1);
        u = h * WW + t * PW + x; v = u + 1;
    } else {
        int q = e - ROWCOL;
        int t = q / X_PER, l = q - t * X_PER;
        int h = l / PW, x = l - h * PW;
        u = h * WW + t * PW + x; v = u + PW;
    }
}

// root under parent forest; handles unbroken 2-cycles (mutual min edge) by
// rooting the smaller id — exactly the reference's (gp==idx)&(idx<parent) rule.
__device__ __forceinline__ int rootOf(const int* __restrict__ par, int c) {
    while (true) {
        int p = par[c];
        if (p == c) return c;
        int pp = par[p];
        if (pp == c) return c < p ? c : p;
        c = p;
    }
}

__global__ __launch_bounds__(256) void init_kernel(int* comp, int* parent,
                                                   ull* minkey, unsigned char* mask,
                                                   unsigned* aliveW,
                                                   int* found, int* done) {
    int i = blockIdx.x * 256 + threadIdx.x;
    int b = blockIdx.y;
    if (i < NV) {
        comp[(size_t)b*NV + i] = i;
        parent[(size_t)b*NV + i] = i;
        minkey[(size_t)b*NV + i] = ~0ULL;
    }
    if (i < NE) mask[(size_t)b*NE + i] = 0;
    if (i < NWORDS_P) aliveW[(size_t)b*NWORDS_P + i] = 0xffffffffu;
    if (b == 0 && i < NB) { found[i] = 1; found[NB + i] = 0; done[i] = 0; }
}

// Stencil key kernel fused with Borůvka round 0 (~25 us, HBM-bound).
// Thread = vertex (h,x). Computes the 3 incident forward diffs (vertical,
// horizontal, cross) in one pass over channels, writes keys (weight slot ==
// edge id), and — since round-0 components are singletons — atomicMins the
// key straight into minkey[u], minkey[v] using the INDEX-layout endpoints.
__global__ __launch_bounds__(256) void key0_kernel(const float* __restrict__ fm,
                                                   ull* __restrict__ keys,
                                                   ull* __restrict__ minkey) {
    int i = blockIdx.x * 256 + threadIdx.x;
    int b = blockIdx.y;
    if (i >= NV) return;
    int h = i / WW, x = i - h * WW;
    int t = x / PW, xr = x - t * PW;
    bool hv = (h < HH-1);
    bool hh = (xr < PW-1);
    bool hx = (x < WW-PW);
    int ov = hv ? WW : 0;          // invalid -> reload self, diff = 0
    int oh = hh ? 1  : 0;
    int ox = hx ? PW : 0;
    const float* base = fm + (size_t)b * NC * NV + i;
    float sv = 0.f, sh_ = 0.f, sx = 0.f;
    #pragma unroll 8
    for (int ch = 0; ch < NC; ++ch) {
        const float* p = base + (size_t)ch * NV;
        float f0 = p[0];
        float dv = f0 - p[ov];
        float dh = f0 - p[oh];
        float dx = f0 - p[ox];
        sv += dv * dv; sh_ += dh * dh; sx += dx * dx;
    }
    ull* mk = minkey + (size_t)b * NV;
    ull* ky = keys + (size_t)b * NE;
    if (hv) {
        int e = t * PAIRW + h * PW + xr;
        ull k = ((ull)__float_as_uint(sv) << 32) | (unsigned int)e;
        ky[e] = k;
        int u, v; index_uv(e, u, v);
        atomicMin(&mk[u], k); atomicMin(&mk[v], k);
    }
    if (hh) {
        int e = t * PAIRW + R_PER + h * (PW-1) + xr;
        ull k = ((ull)__float_as_uint(sh_) << 32) | (unsigned int)e;
        ky[e] = k;
        int u, v; index_uv(e, u, v);
        atomicMin(&mk[u], k); atomicMin(&mk[v], k);
    }
    if (hx) {
        int e = ROWCOL + t * X_PER + h * PW + xr;
        ull k = ((ull)__float_as_uint(sx) << 32) | (unsigned int)e;
        ky[e] = k;
        int u, v; index_uv(e, u, v);
        atomicMin(&mk[u], k); atomicMin(&mk[v], k);
    }
}

// One Borůvka scan over all edges, coalesced. Dead edges exit on a broadcast
// bitmask word read; deaths are folded back via wave ballot (no atomics).
// Bitmask slab is padded to NEP per batch so a wave's two ballot words are
// always inside its own batch (fixes v5's OOB cross-batch clobber).
__global__ __launch_bounds__(256) void scan_kernel(const ull* __restrict__ keys,
                                                   int* __restrict__ comp,
                                                   const int* __restrict__ parent,
                                                   ull* __restrict__ minkey,
                                                   unsigned* __restrict__ aliveW,
                                                   int* __restrict__ foundCur,
                                                   const int* __restrict__ done) {
    int e = blockIdx.x * 256 + threadIdx.x;
    int b = blockIdx.y;
    if (done[b]) return;                         // converged: scalar read + exit
    const int lane = threadIdx.x & 63;
    unsigned* aw = aliveW + (size_t)b * NWORDS_P;
    bool was = false, live = false;
    int cu = 0, cv = 0;
    if (e < NE) was = (aw[e >> 5] >> (e & 31)) & 1;
    if (was) {
        const int* par = parent + (size_t)b * NV;
        int* cmp = comp + (size_t)b * NV;
        int u, v; index_uv(e, u, v);
        cu = rootOf(par, cmp[u]); if (cmp[u] != cu) cmp[u] = cu;  // benign race
        cv = rootOf(par, cmp[v]); if (cmp[v] != cv) cmp[v] = cv;
        live = (cu != cv);
    }
    if (live) {
        ull k = keys[(size_t)b * NE + e];
        ull* mk = minkey + (size_t)b * NV;
        if (k < mk[cu]) atomicMin(&mk[cu], k);   // pre-check kills hot-slot serialization
        if (k < mk[cv]) atomicMin(&mk[cv], k);
    }
    ull ball = __ballot(live ? 1 : 0);
    ull ballWas = __ballot(was ? 1 : 0);
    if (ball != ballWas) {                       // deaths in this wave: rewrite 2 words
        int wbase = (blockIdx.x * 256 + (threadIdx.x & ~63)) >> 5;  // < NWORDS_P-1
        if (lane == 0)  aw[wbase]     = (unsigned)ball;
        if (lane == 32) aw[wbase + 1] = (unsigned)(ball >> 32);
    }
    if (ball && lane == __ffsll((long long)ball) - 1)
        foundCur[b] = 1;                         // one store per wave
}

// Per component: read winning edge, mark mask, hook parent, reset minkey.
// fc==0 => scan found nothing => minkey untouched and hooks idempotent: set
// done, skip. foundNext is reset for the round after next.
__global__ __launch_bounds__(256) void select_kernel(const int* __restrict__ comp,
                                                     int* __restrict__ parent,
                                                     ull* __restrict__ minkey,
                                                     unsigned char* __restrict__ mask,
                                                     const int* __restrict__ foundCur,
                                                     int* __restrict__ foundNext,
                                                     int* __restrict__ done) {
    int c = blockIdx.x * 256 + threadIdx.x;
    int b = blockIdx.y;
    int fc = foundCur[b];
    if (c == 0) {
        foundNext[b] = 0;
        if (fc == 0) done[b] = 1;                // monotone; visible to later scans
    }
    if (fc == 0) return;
    if (c >= NV) return;
    size_t off = (size_t)b * NV;
    ull k = minkey[off + c];
    int par = c;
    if (k != ~0ULL) {
        minkey[off + c] = ~0ULL;                 // reset only touched slots
        int e = (int)(k & 0xffffffffu);
        mask[(size_t)b * NE + e] = 1;            // idempotent
        int u, v; index_uv(e, u, v);
        int cu = comp[off + u], cv = comp[off + v];
        par = (cu == c) ? cv : cu;               // "other" component
    }
    if (parent[off + c] != par) parent[off + c] = par;
}

__global__ __launch_bounds__(256) void count_kernel(const unsigned char* __restrict__ mask,
                                                    int* __restrict__ counts) {
    int b = blockIdx.y, ck = blockIdx.x, t = threadIdx.x;
    const unsigned char* m = mask + (size_t)b * NE;
    int base_e = ck * CHUNK + t * 16;
    int cnt = 0;
    #pragma unroll
    for (int i = 0; i < 16; ++i) {
        int e = base_e + i;
        if (e < NE && m[e]) cnt++;
    }
    __shared__ int sh[256];
    sh[t] = cnt;
    __syncthreads();
    for (int o = 128; o > 0; o >>= 1) {
        if (t < o) sh[t] += sh[t + o];
        __syncthreads();
    }
    if (t == 0) counts[b * NCHUNK + ck] = sh[0];
}

// Write with inline offset computation (reduce over counts[0..ck-1]) — no
// separate offs kernel.
__global__ __launch_bounds__(256) void write_kernel(const unsigned char* __restrict__ mask,
                                                    const int* __restrict__ counts,
                                                    int* __restrict__ out) {
    int b = blockIdx.y, ck = blockIdx.x, t = threadIdx.x;
    __shared__ int sh[256];
    __shared__ int shOff[128];
    // block offset = sum of counts for chunks < ck (NCHUNK=86 < 128)
    shOff[t & 127] = 0;
    __syncthreads();
    if (t < NCHUNK && t < ck) shOff[t] = counts[b * NCHUNK + t];
    __syncthreads();
    for (int o = 64; o > 0; o >>= 1) {
        if (t < o) shOff[t] += shOff[t + o];
        __syncthreads();
    }
    int blockOff = shOff[0];

    const unsigned char* m = mask + (size_t)b * NE;
    int base_e = ck * CHUNK + t * 16;
    int cnt = 0;
    #pragma unroll
    for (int i = 0; i < 16; ++i) {
        int e = base_e + i;
        if (e < NE && m[e]) cnt++;
    }
    sh[t] = cnt;
    __syncthreads();
    for (int o = 1; o < 256; o <<= 1) {          // Hillis-Steele inclusive scan
        int v = 0;
        if (t >= o) v = sh[t - o];
        __syncthreads();
        sh[t] += v;
        __syncthreads();
    }
    int pos = blockOff + (sh[t] - cnt);
    for (int i = 0; i < 16; ++i) {
        int e = base_e + i;
        if (e < NE && m[e]) {
            if (pos < NTREE) out[(size_t)b * NTREE + pos] = e;
            pos++;
        }
    }
}

extern "C" void kernel_launch(void* const* d_in, const int* in_sizes, int n_in,
                              void* d_out, int out_size, void* d_ws, size_t ws_size,
                              hipStream_t stream) {
    const float* fm = (const float*)d_in[0];
    int* out = (int*)d_out;   // reference output dtype is int32

    char* ws = (char*)d_ws;
    size_t off = 0;
    auto alloc = [&](size_t bytes) -> void* {
        void* p = ws + off;
        off += (bytes + 255) & ~(size_t)255;
        return p;
    };
    ull* keys    = (ull*)alloc((size_t)NB * NE * 8);
    ull* minkey  = (ull*)alloc((size_t)NB * NV * 8);
    int* comp    = (int*)alloc((size_t)NB * NV * 4);
    int* parent  = (int*)alloc((size_t)NB * NV * 4);
    unsigned char* mask = (unsigned char*)alloc((size_t)NB * NE);
    unsigned* aliveW = (unsigned*)alloc((size_t)NB * NWORDS_P * 4);
    int* counts  = (int*)alloc((size_t)NB * NCHUNK * 4);
    int* found   = (int*)alloc(2 * NB * 4);
    int* done    = (int*)alloc(NB * 4);

    dim3 blk(256);
    dim3 gE(NEB, NB);
    dim3 gV((NV + 255) / 256, NB);

    init_kernel<<<gE, blk, 0, stream>>>(comp, parent, minkey, mask, aliveW, found, done);
    key0_kernel<<<gV, blk, 0, stream>>>(fm, keys, minkey);

    // Round 0 select (found[0..NB) preset to 1 by init; comp = identity).
    select_kernel<<<gV, blk, 0, stream>>>(comp, parent, minkey, mask,
                                          found, found + NB, done);
    // Rounds 1..17
    for (int r = 1; r < NROUNDS; ++r) {
        int* fCur  = found + (r & 1) * NB;
        int* fNext = found + ((r + 1) & 1) * NB;
        scan_kernel<<<gE, blk, 0, stream>>>(keys, comp, parent, minkey, aliveW,
                                            fCur, done);
        select_kernel<<<gV, blk, 0, stream>>>(comp, parent, minkey, mask,
                                              fCur, fNext, done);
    }

    count_kernel<<<dim3(NCHUNK, NB), blk, 0, stream>>>(mask, counts);
    write_kernel<<<dim3(NCHUNK, NB), blk, 0, stream>>>(mask, counts, out);
}